// Round 1
// baseline (172.703 us; speedup 1.0000x reference)
//
#include <hip/hip_runtime.h>
#include <stdint.h>

#define SLEN 4096
#define BATCH 4
#define DIM 64
#define HPROJ 16
#define PREFIX 6
#define KMAX 64

// ---------------- Phase 1: per-token hash / sign-bits / inserted ----------------
__global__ void __launch_bounds__(256) phase1_kernel(
    const float* __restrict__ qup, const float* __restrict__ kup,
    const float* __restrict__ W,
    unsigned char* __restrict__ qh, unsigned char* __restrict__ kh,
    unsigned long long* __restrict__ qsig, unsigned long long* __restrict__ ksig,
    unsigned char* __restrict__ inserted)
{
    __shared__ float Ws[DIM * HPROJ];
    for (int i = threadIdx.x; i < DIM * HPROJ; i += blockDim.x) Ws[i] = W[i];
    __syncthreads();

    int tid = blockIdx.x * blockDim.x + threadIdx.x;   // 0 .. 2*B*S-1
    if (tid >= 2 * BATCH * SLEN) return;
    int tensor = tid / (BATCH * SLEN);                 // 0 = query, 1 = key
    int rem    = tid % (BATCH * SLEN);
    int b = rem / SLEN;
    int s = rem % SLEN;

    const float* x = (tensor ? kup : qup) + (size_t)rem * DIM;

    float xr[DIM];
    unsigned long long bits = 0ull;
#pragma unroll
    for (int d = 0; d < DIM; ++d) {
        xr[d] = x[d];
        if (xr[d] > 0.0f) bits |= (1ull << d);
    }

    int acc = 0;
    for (int h = 0; h < HPROJ; ++h) {
        float p = 0.0f;
#pragma unroll
        for (int d = 0; d < DIM; ++d) p = fmaf(xr[d], Ws[d * HPROJ + h], p);
        // floor(p / 4.0): division by 4 is exact in fp32
        acc += (int)floorf(p * 0.25f);
    }
    // Python-style mod 64 == bitwise and with 63 (two's complement)
    unsigned char hash = (unsigned char)(acc & 63);

    if (tensor == 0) {
        qh[rem] = hash;
        if (b == BATCH - 1) qsig[s] = bits;
    } else {
        kh[rem] = hash;
        if (b == BATCH - 1) ksig[s] = bits;
        if (b == 0) {
            // Wu-Manber: prefix sign match between q[0,s,:6] and k[0,s,:6]
            const float* qq = qup + (size_t)s * DIM;   // batch 0, token s
            int ok = 1;
#pragma unroll
            for (int j = 0; j < PREFIX; ++j)
                ok &= ((qq[j] > 0.0f) == (xr[j] > 0.0f));
            inserted[s] = (unsigned char)ok;
        }
    }
}

// ---------------- Phase 2: per (b,q) scan + exact top-k ----------------
__global__ void __launch_bounds__(64) phase2_kernel(
    const float* __restrict__ qup, const float* __restrict__ kup,
    const unsigned char* __restrict__ qh, const unsigned char* __restrict__ kh,
    const unsigned long long* __restrict__ qsig,
    const unsigned long long* __restrict__ ksig,
    const unsigned char* __restrict__ inserted,
    int* __restrict__ out)
{
    __shared__ float vals[SLEN];
    __shared__ int   idxs[SLEN];
    __shared__ int   count;

    int bq   = blockIdx.x;            // 0 .. B*S-1
    int b    = bq >> 12;              // / SLEN
    int qrow = bq & (SLEN - 1);
    int tid  = threadIdx.x;           // 0..63

    if (tid == 0) count = 0;
    // default output: -1 (thread t owns slot t; exactly KMAX==64 threads)
    out[(size_t)bq * KMAX + tid] = -1;

    unsigned long long qsv = qsig[qrow];
    int qhv = (int)qh[bq];
    __syncthreads();

    const float* qr = qup + ((size_t)b * SLEN + qrow) * DIM;

    for (int k = tid; k < SLEN; k += 64) {
        // cheapest / most selective test first: exact 64-bit sign match (batch 3)
        if (ksig[k] == qsv) {
            if (inserted[k] && (int)kh[b * SLEN + k] == qhv) {
                const float* kr = kup + ((size_t)b * SLEN + k) * DIM;
                float sim = 0.0f;
#pragma unroll
                for (int d = 0; d < DIM; ++d) sim = fmaf(qr[d], kr[d], sim);
                int p = atomicAdd(&count, 1);   // p < SLEN always (each k once)
                vals[p] = sim;
                idxs[p] = k;
            }
        }
    }
    __syncthreads();

    int m = count;
    for (int i = tid; i < m; i += 64) {
        float vi = vals[i];
        int   ii = idxs[i];
        int rank = 0;
        for (int j = 0; j < m; ++j) {
            float vj = vals[j];
            rank += (vj > vi) || (vj == vi && idxs[j] < ii);
        }
        if (rank < KMAX) out[(size_t)bq * KMAX + rank] = ii;
    }
}

extern "C" void kernel_launch(void* const* d_in, const int* in_sizes, int n_in,
                              void* d_out, int out_size, void* d_ws, size_t ws_size,
                              hipStream_t stream)
{
    const float* qup = (const float*)d_in[0];
    const float* kup = (const float*)d_in[1];
    const float* W   = (const float*)d_in[2];
    // d_in[3] = head_idx (unused by the reference)
    int* out = (int*)d_out;

    // workspace layout (8B-aligned arrays first): total ~100 KB
    char* w = (char*)d_ws;
    unsigned long long* qsig = (unsigned long long*)(w);            // 32 KB
    unsigned long long* ksig = (unsigned long long*)(w + 32768);    // 32 KB
    unsigned char* qh  = (unsigned char*)(w + 65536);               // 16 KB
    unsigned char* kh  = (unsigned char*)(w + 65536 + 16384);       // 16 KB
    unsigned char* ins = (unsigned char*)(w + 65536 + 32768);       // 4 KB

    phase1_kernel<<<(2 * BATCH * SLEN + 255) / 256, 256, 0, stream>>>(
        qup, kup, W, qh, kh, qsig, ksig, ins);
    phase2_kernel<<<BATCH * SLEN, 64, 0, stream>>>(
        qup, kup, qh, kh, qsig, ksig, ins, out);
}

// Round 2
// 20.395 us; speedup vs baseline: 8.4679x; 8.4679x over previous
//
#include <hip/hip_runtime.h>
#include <stdint.h>

#define SLEN   4096
#define BATCH  4
#define DIM    64
#define HPROJ  16
#define PREFIX 6
#define KMAX   64

#define HSLOTS   8192
#define HMASK    8191
#define PAIR_CAP 16384

// ---------------- K0: init hash-table head + pair counter ----------------
__global__ void __launch_bounds__(256) k_init(int* __restrict__ head, int* __restrict__ pc)
{
    int i = blockIdx.x * 256 + threadIdx.x;
    if (i < HSLOTS) head[i] = -1;
    if (i == 0) *pc = 0;
}

// ---------------- K1: per-token hash/signature + table insert + out init ----------------
// 8 threads per token (2 LSH projections each), shuffle-reduced.
__global__ void __launch_bounds__(256) k_phase1(
    const float* __restrict__ qup, const float* __restrict__ kup,
    const float* __restrict__ W,
    unsigned char* __restrict__ qh, unsigned char* __restrict__ kh,
    unsigned long long* __restrict__ qsig, unsigned long long* __restrict__ ksig,
    int* __restrict__ head, int* __restrict__ next,
    int* __restrict__ out)
{
    __shared__ float Ws[DIM * HPROJ];
    for (int i = threadIdx.x; i < DIM * HPROJ; i += 256) Ws[i] = W[i];
    __syncthreads();

    int gid = blockIdx.x * 256 + threadIdx.x;          // 0 .. 262143

    // fold the -1 output init into this kernel (4 ints per thread, 4 MB total)
    for (int o = gid; o < BATCH * SLEN * KMAX; o += 2 * BATCH * SLEN * 8)
        out[o] = -1;

    int token  = gid >> 3;                             // 0 .. 32767
    int hg     = gid & 7;                              // projection group
    int tensor = token >> 14;                          // 0 = query, 1 = key  (B*S = 16384)
    int rem    = token & (BATCH * SLEN - 1);
    int b      = rem >> 12;
    int s      = rem & (SLEN - 1);

    const float* x = (tensor ? kup : qup) + (size_t)rem * DIM;

    float4 xv[DIM / 4];
#pragma unroll
    for (int dv = 0; dv < DIM / 4; ++dv)
        xv[dv] = ((const float4*)x)[dv];

    int h0 = hg * 2;
    float p0 = 0.0f, p1 = 0.0f;
#pragma unroll
    for (int dv = 0; dv < DIM / 4; ++dv) {
        float4 v = xv[dv];
        int d = dv * 4;
        p0 = fmaf(v.x, Ws[(d + 0) * HPROJ + h0], p0);
        p0 = fmaf(v.y, Ws[(d + 1) * HPROJ + h0], p0);
        p0 = fmaf(v.z, Ws[(d + 2) * HPROJ + h0], p0);
        p0 = fmaf(v.w, Ws[(d + 3) * HPROJ + h0], p0);
        p1 = fmaf(v.x, Ws[(d + 0) * HPROJ + h0 + 1], p1);
        p1 = fmaf(v.y, Ws[(d + 1) * HPROJ + h0 + 1], p1);
        p1 = fmaf(v.z, Ws[(d + 2) * HPROJ + h0 + 1], p1);
        p1 = fmaf(v.w, Ws[(d + 3) * HPROJ + h0 + 1], p1);
    }
    // floor(p/4): /4 exact in fp32
    int acc = (int)floorf(p0 * 0.25f) + (int)floorf(p1 * 0.25f);
    acc += __shfl_xor(acc, 1);
    acc += __shfl_xor(acc, 2);
    acc += __shfl_xor(acc, 4);

    if (hg == 0) {
        unsigned char hash = (unsigned char)(acc & 63);   // Python mod 64
        if (!tensor) qh[rem] = hash; else kh[rem] = hash;

        if (b == BATCH - 1) {
            unsigned long long bits = 0ull;
#pragma unroll
            for (int dv = 0; dv < DIM / 4; ++dv) {
                float4 v = xv[dv];
                int d = dv * 4;
                if (v.x > 0.0f) bits |= (1ull << (d + 0));
                if (v.y > 0.0f) bits |= (1ull << (d + 1));
                if (v.z > 0.0f) bits |= (1ull << (d + 2));
                if (v.w > 0.0f) bits |= (1ull << (d + 3));
            }
            if (!tensor) {
                qsig[s] = bits;
            } else {
                ksig[s] = bits;
                // Wu-Manber filter: sign-prefix match between q[0,s,:6] and k[0,s,:6]
                const float* q0 = qup + (size_t)s * DIM;
                const float* k0 = kup + (size_t)s * DIM;
                bool ins = true;
#pragma unroll
                for (int j = 0; j < PREFIX; ++j)
                    ins &= ((q0[j] > 0.0f) == (k0[j] > 0.0f));
                if (ins) {
                    int h = (int)(bits & HMASK);
                    next[s] = atomicExch(&head[h], s);   // chain insert
                }
            }
        }
    }
}

// ---------------- K2: probe table, expand over batches, emit candidate pairs ----------------
__global__ void __launch_bounds__(256) k_probe(
    const unsigned long long* __restrict__ qsig,
    const unsigned long long* __restrict__ ksig,
    const unsigned char* __restrict__ qh, const unsigned char* __restrict__ kh,
    const int* __restrict__ head, const int* __restrict__ next,
    int* __restrict__ pc, unsigned int* __restrict__ pairs)
{
    int q = blockIdx.x * 256 + threadIdx.x;
    if (q >= SLEN) return;
    unsigned long long sv = qsig[q];
    for (int k = head[(int)(sv & HMASK)]; k != -1; k = next[k]) {
        if (ksig[k] == sv) {
            for (int b = 0; b < BATCH; ++b) {
                if (qh[b * SLEN + q] == kh[b * SLEN + k]) {
                    int p = atomicAdd(pc, 1);
                    if (p < PAIR_CAP)
                        pairs[p] = ((unsigned)b << 24) | ((unsigned)q << 12) | (unsigned)k;
                }
            }
        }
    }
}

// ---------------- K3: exact top-k rank among surviving pairs ----------------
__device__ inline float dot64(const float* a, const float* b)
{
    float s = 0.0f;
#pragma unroll
    for (int d = 0; d < DIM; ++d) s = fmaf(a[d], b[d], s);
    return s;
}

__global__ void __launch_bounds__(256) k_emit(
    const float* __restrict__ qup, const float* __restrict__ kup,
    const int* __restrict__ pc, const unsigned int* __restrict__ pairs,
    int* __restrict__ out)
{
    int n = *pc;
    if (n > PAIR_CAP) n = PAIR_CAP;
    for (int i = threadIdx.x; i < n; i += 256) {
        unsigned u = pairs[i];
        int b = u >> 24, q = (u >> 12) & 4095, k = u & 4095;
        const float* qr = qup + ((size_t)(b * SLEN + q)) * DIM;
        float si = dot64(qr, kup + ((size_t)(b * SLEN + k)) * DIM);
        int rank = 0;
        for (int j = 0; j < n; ++j) {
            unsigned v = pairs[j];
            if ((v >> 12) == (u >> 12)) {                 // same (b, q)
                int kj = v & 4095;
                float sj = dot64(qr, kup + ((size_t)(b * SLEN + kj)) * DIM);
                rank += (sj > si) || (sj == si && kj < k);
            }
        }
        if (rank < KMAX)
            out[((size_t)(b * SLEN + q)) * KMAX + rank] = k;
    }
}

extern "C" void kernel_launch(void* const* d_in, const int* in_sizes, int n_in,
                              void* d_out, int out_size, void* d_ws, size_t ws_size,
                              hipStream_t stream)
{
    const float* qup = (const float*)d_in[0];
    const float* kup = (const float*)d_in[1];
    const float* W   = (const float*)d_in[2];
    int* out = (int*)d_out;

    char* w = (char*)d_ws;
    unsigned long long* qsig = (unsigned long long*)(w);             // 32 KB
    unsigned long long* ksig = (unsigned long long*)(w + 32768);     // 32 KB
    int*           head = (int*)(w + 65536);                         // 32 KB
    int*           next = (int*)(w + 98304);                         // 16 KB
    unsigned char* qh   = (unsigned char*)(w + 114688);              // 16 KB
    unsigned char* kh   = (unsigned char*)(w + 131072);              // 16 KB
    int*           pc   = (int*)(w + 147456);                        // 4 B
    unsigned int*  pairs= (unsigned int*)(w + 147520);               // 64 KB

    k_init<<<HSLOTS / 256, 256, 0, stream>>>(head, pc);
    k_phase1<<<(2 * BATCH * SLEN * 8) / 256, 256, 0, stream>>>(
        qup, kup, W, qh, kh, qsig, ksig, head, next, out);
    k_probe<<<SLEN / 256, 256, 0, stream>>>(qsig, ksig, qh, kh, head, next, pc, pairs);
    k_emit<<<1, 256, 0, stream>>>(qup, kup, pc, pairs, out);
}